// Round 8
// baseline (338.920 us; speedup 1.0000x reference)
//
#include <hip/hip_runtime.h>
#include <cstdint>

typedef unsigned short u16;
typedef short bf16x8 __attribute__((ext_vector_type(8)));
typedef float f32x4 __attribute__((ext_vector_type(4)));

#define NB 4
#define SEQ 2048
#define DMODEL 1024
#define NHEADS 16
#define DHEAD 64
#define BHTOT (NB*NHEADS)   // 64
#define MROWS (NB*SEQ)      // 8192

__device__ __forceinline__ float bf2f(u16 u){
  union { unsigned int i; float f; } x; x.i = ((unsigned int)u)<<16; return x.f;
}
__device__ __forceinline__ u16 f2bf(float f){
  union { float f; unsigned int i; } x; x.f = f;
  unsigned int r = x.i + 0x7fffu + ((x.i>>16)&1u);
  return (u16)(r>>16);
}
__device__ __forceinline__ u16 f2bf_trunc(float f){   // for P: >=0, consistent num/denom
  union { float f; unsigned int i; } x; x.f = f;
  return (u16)(x.i>>16);
}

typedef const __attribute__((address_space(1))) unsigned int* gas_t;
typedef __attribute__((address_space(3))) unsigned int* las_t;
__device__ __forceinline__ void async_cp16(const void* g, void* l){
  __builtin_amdgcn_global_load_lds((gas_t)g, (las_t)l, 16, 0, 0);
}

// ---------------- fp32 -> bf16 cast for BOTH weights (one launch) ----------------
__global__ __launch_bounds__(256) void cast2_kernel(const float* __restrict__ wa, u16* __restrict__ oa,
    const float* __restrict__ wb, u16* __restrict__ ob, int na4){
  int i = blockIdx.x*256 + threadIdx.x;
  const float* src; u16* dst; int j;
  if(i < na4){ src = wa; dst = oa; j = i; }
  else       { src = wb; dst = ob; j = i - na4; }
  float4 v = ((const float4*)src)[j];
  ushort4 o;
  o.x=f2bf(v.x); o.y=f2bf(v.y); o.z=f2bf(v.z); o.w=f2bf(v.w);
  ((ushort4*)dst)[j] = o;
}

// ---------------- LayerNorm: x fp32 -> h bf16 (f32 stats) ----------------
__global__ __launch_bounds__(256) void ln_kernel(const float* __restrict__ x, u16* __restrict__ h){
  int row = blockIdx.x;
  const float* xr = x + (size_t)row*DMODEL;
  u16* hr = h + (size_t)row*DMODEL;
  int t = threadIdx.x;
  float4 v = ((const float4*)xr)[t];
  float f0=v.x, f1=v.y, f2=v.z, f3=v.w;
  float s = f0+f1+f2+f3;
  float q = f0*f0+f1*f1+f2*f2+f3*f3;
  #pragma unroll
  for(int off=32; off; off>>=1){ s += __shfl_xor(s, off); q += __shfl_xor(q, off); }
  __shared__ float ss[4], sq[4];
  int wv = t>>6, lane = t&63;
  if(lane==0){ ss[wv]=s; sq[wv]=q; }
  __syncthreads();
  s = ss[0]+ss[1]+ss[2]+ss[3];
  q = sq[0]+sq[1]+sq[2]+sq[3];
  float mu  = s * (1.0f/DMODEL);
  float var = q * (1.0f/DMODEL) - mu*mu;
  float rs  = rsqrtf(var + 1e-8f);
  ushort4 o;
  o.x=f2bf((f0-mu)*rs); o.y=f2bf((f1-mu)*rs); o.z=f2bf((f2-mu)*rs); o.w=f2bf((f3-mu)*rs);
  ((ushort4*)hr)[t] = o;
}

// ---------------- GEMM: C[m,n] = sum_k A[m,k]*Bm[n,k], bf16 MFMA ----------------
#define BM 128
#define BN 128
#define BK 32

template<int MODE>
__global__ __launch_bounds__(256) void gemm_bt(const u16* __restrict__ A, const u16* __restrict__ Bm,
    u16* __restrict__ Qb, u16* __restrict__ Kb, u16* __restrict__ Vtb, float* __restrict__ outf,
    int M, int N, int K){
  __shared__ u16 As[BM*BK];
  __shared__ u16 Bs[BN*BK];
  int t = threadIdx.x;
  int lane = t&63, wv = t>>6;
  int c = lane&15, g = lane>>4;
  int wm = wv>>1, wn = wv&1;
  int m0 = blockIdx.y*BM, n0 = blockIdx.x*BN;
  f32x4 acc[4][4] = {};
  for(int k0=0;k0<K;k0+=BK){
    __syncthreads();
    #pragma unroll
    for(int i=0;i<2;i++){
      int e = t*8 + i*2048;
      int r = e>>5, col = e&31;
      async_cp16(&A [(size_t)(m0+r)*K + k0 + col], &As[e]);
      async_cp16(&Bm[(size_t)(n0+r)*K + k0 + col], &Bs[e]);
    }
    __syncthreads();
    bf16x8 af[4], bfr[4];
    #pragma unroll
    for(int i=0;i<4;i++){
      af[i]  = *(const bf16x8*)(&As[(wm*64 + i*16 + c)*BK + g*8]);
      bfr[i] = *(const bf16x8*)(&Bs[(wn*64 + i*16 + c)*BK + g*8]);
    }
    #pragma unroll
    for(int mi=0;mi<4;mi++)
      #pragma unroll
      for(int ni=0;ni<4;ni++)
        acc[mi][ni] = __builtin_amdgcn_mfma_f32_16x16x32_bf16(af[mi], bfr[ni], acc[mi][ni], 0,0,0);
  }
  if(MODE==1){
    #pragma unroll
    for(int mi=0;mi<4;mi++){
      int mrow = m0 + wm*64 + mi*16 + g*4;
      #pragma unroll
      for(int ni=0;ni<4;ni++){
        int ncol = n0 + wn*64 + ni*16 + c;
        #pragma unroll
        for(int r=0;r<4;r++)
          outf[(size_t)(mrow+r)*N + ncol] = acc[mi][ni][r];
      }
    }
  } else {
    #pragma unroll
    for(int ni=0;ni<4;ni++){
      int n = n0 + wn*64 + ni*16 + c;
      int sel = n>>10, head = (n>>6)&15, d = n&63;
      #pragma unroll
      for(int mi=0;mi<4;mi++){
        int m = m0 + wm*64 + mi*16 + g*4;
        int b = m>>11, l = m&(SEQ-1);
        if(sel<2){
          u16* dst = (sel==0?Qb:Kb) + ((size_t)((b*NHEADS+head)*SEQ + l))*DHEAD + d;
          #pragma unroll
          for(int r=0;r<4;r++) dst[(size_t)r*DHEAD] = f2bf(acc[mi][ni][r]);
        } else {
          ushort4 pk;
          pk.x=f2bf(acc[mi][ni][0]); pk.y=f2bf(acc[mi][ni][1]);
          pk.z=f2bf(acc[mi][ni][2]); pk.w=f2bf(acc[mi][ni][3]);
          *(ushort4*)(&Vtb[((size_t)((b*NHEADS+head)*DHEAD + d))*SEQ + l]) = pk;
        }
      }
    }
  }
}

// ---------------- RoPE: one thread per (l,j), sincos once, loop over bh ----------------
// Q additionally pre-scaled by scale*log2(e) so attn's softmax is a bare exp2.
#define SC2 0.180336879f   // 0.125 * log2(e)
__global__ __launch_bounds__(256) void rope_kernel(u16* __restrict__ Q, u16* __restrict__ Kb){
  int tid = blockIdx.x*256 + threadIdx.x;   // SEQ*32 threads
  int j = tid&31, l = tid>>5;
  float inv = exp2f(-(float)j * (13.28771237954945f/32.0f)); // 10000^(-j/32)
  float sn, cs;
  sincosf((float)l*inv, &sn, &cs);
  size_t base = (size_t)l*DHEAD + 2*j;
  #pragma unroll 4
  for(int bh=0; bh<BHTOT; bh++){
    size_t off = base + (size_t)bh*SEQ*DHEAD;
    ushort2 q2 = *(ushort2*)(&Q[off]);
    float x1=bf2f(q2.x), x2=bf2f(q2.y);
    ushort2 o;
    o.x = f2bf((x1*cs - x2*sn)*SC2); o.y = f2bf((x1*sn + x2*cs)*SC2);
    *(ushort2*)(&Q[off]) = o;
    ushort2 k2 = *(ushort2*)(&Kb[off]);
    x1=bf2f(k2.x); x2=bf2f(k2.y);
    o.x = f2bf(x1*cs - x2*sn); o.y = f2bf(x1*sn + x2*cs);
    *(ushort2*)(&Kb[off]) = o;
  }
}

// ---------------- Flash attention: K-split waves, pipelined PV, tiny LDS ----------------
// Block = 128 threads (2 waves) owns one 32-row q strip s; causal range s+1 KV
// tiles split between waves; exact add-merge (no online max; scores bounded,
// Q pre-scaled so P = exp2(S)). PV runs one tile behind exp. SINGLE P buffer
// per wave: every PREAD(t-1) is issued before the EXPW(t) overwrite and LDS is
// in-order per wave => WAR safe. Osum/Lsum ALIAS the P region (P dead at merge;
// guarded by an extra __syncthreads). LDS 8.6 KB/block => ~10 blocks/CU resident
// (VGPR-bound), vs 18.9 KB before.
#define PSTR 40   // P scratch row stride (elems)
#define OSTR 66   // Osum row stride (floats)

#define LOADK(TILE, KF) { \
  int tb_ = (TILE)*32; \
  _Pragma("unroll") for(int nf_=0;nf_<2;nf_++) \
    _Pragma("unroll") for(int ks_=0;ks_<2;ks_++) \
      KF[nf_][ks_] = *(const bf16x8*)(&Kp[(size_t)(tb_ + nf_*16 + c)*DHEAD + ks_*32 + g*8]); }

#define LOADV(TILE, VF) { \
  int tb_ = (TILE)*32; \
  _Pragma("unroll") for(int df_=0;df_<4;df_++) \
    VF[df_] = *(const bf16x8*)(&Vp[(size_t)(df_*16 + c)*SEQ + tb_ + g*8]); }

#define QKS(SC, KF) { \
  _Pragma("unroll") for(int mt_=0;mt_<2;mt_++) \
    _Pragma("unroll") for(int nf_=0;nf_<2;nf_++){ \
      f32x4 z_ = {0.f,0.f,0.f,0.f}; \
      f32x4 a_ = __builtin_amdgcn_mfma_f32_16x16x32_bf16(qf[mt_][0], KF[nf_][0], z_,0,0,0); \
      SC[mt_][nf_] = __builtin_amdgcn_mfma_f32_16x16x32_bf16(qf[mt_][1], KF[nf_][1], a_,0,0,0); } }

#define EXPW(SC, TILE) { \
  bool dm_ = ((TILE) == s); \
  _Pragma("unroll") for(int mt_=0;mt_<2;mt_++) \
    _Pragma("unroll") for(int nf_=0;nf_<2;nf_++) \
      _Pragma("unroll") for(int r_=0;r_<4;r_++){ \
        float e_ = exp2f(SC[mt_][nf_][r_]); \
        if(dm_) e_ = (nf_*16 + c <= mt_*16 + g*4 + r_) ? e_ : 0.f; \
        LP[(mt_*16 + g*4 + r_)*PSTR + nf_*16 + c] = f2bf_trunc(e_); } }

#define PREAD(PA) { \
  _Pragma("unroll") for(int mt_=0;mt_<2;mt_++) \
    PA[mt_] = *(const bf16x8*)(&LP[(mt_*16 + c)*PSTR + g*8]); }

#define PVM(PA, VF) { \
  _Pragma("unroll") for(int mt_=0;mt_<2;mt_++){ \
    lacc[mt_] = __builtin_amdgcn_mfma_f32_16x16x32_bf16(PA[mt_], ones, lacc[mt_], 0,0,0); \
    _Pragma("unroll") for(int df_=0;df_<4;df_++) \
      oacc[mt_][df_] = __builtin_amdgcn_mfma_f32_16x16x32_bf16(PA[mt_], VF[df_], oacc[mt_][df_], 0,0,0); } }

__global__ __launch_bounds__(128) void attn_kernel(const u16* __restrict__ Q, const u16* __restrict__ Kb,
    const u16* __restrict__ Vt, u16* __restrict__ O){
  // P: 2 waves x 32*PSTR u16 = 5120 B.  Merge area (aliased): 32*OSTR f32 + 32 f32 = 8576 B.
  __shared__ __align__(16) unsigned char smem[32*OSTR*4 + 32*4];
  int t = threadIdx.x, lane = t&63, w = t>>6;
  int c = lane&15, g = lane>>4;
  u16* LP = (u16*)(smem + w*(32*PSTR*2));
  float* Osum = (float*)smem;
  float* Lsum = (float*)(smem + 32*OSTR*4);
  int bh = blockIdx.x;
  int b = bh>>4, hh = bh&15;
  int s = 63 - blockIdx.y;       // long strips first
  int wrow = s*32;
  int nt = s+1;
  int h0 = (nt+1)>>1;
  int tbeg = w ? h0 : 0;
  int tend = w ? nt : h0;
  const u16* Qp = Q  + (size_t)bh*SEQ*DHEAD;
  const u16* Kp = Kb + (size_t)bh*SEQ*DHEAD;
  const u16* Vp = Vt + (size_t)bh*DHEAD*SEQ;
  bf16x8 ones;
  #pragma unroll
  for(int i=0;i<8;i++) ones[i] = (short)0x3f80;  // bf16 1.0

  bf16x8 qf[2][2];
  #pragma unroll
  for(int mt=0;mt<2;mt++)
    #pragma unroll
    for(int ks=0;ks<2;ks++)
      qf[mt][ks] = *(const bf16x8*)(&Qp[(size_t)(wrow + mt*16 + c)*DHEAD + ks*32 + g*8]);

  f32x4 oacc[2][4] = {};
  f32x4 lacc[2] = {};
  bf16x8 kA[2][2], kB[2][2], vA[4], vB[4], pa[2];
  f32x4 sc[2][2];
  int ntw = tend - tbeg;
  if(ntw > 0){
    // prologue: tile tbeg
    LOADK(tbeg, kA); LOADV(tbeg, vA);
    QKS(sc, kA);
    if(ntw > 1) LOADK(tbeg+1, kB);
    EXPW(sc, tbeg);
    int i = 1;
    #pragma unroll 1
    while(i+1 < ntw){
      // tile tbeg+i (kB); PV of tile tbeg+i-1 (vA)
      LOADV(tbeg+i, vB);
      LOADK(tbeg+i+1, kA);
      QKS(sc, kB);
      PREAD(pa);
      EXPW(sc, tbeg+i);
      PVM(pa, vA);
      // tile tbeg+i+1 (kA); PV of tile tbeg+i (vB)
      LOADV(tbeg+i+1, vA);
      if(i+2 < ntw) LOADK(tbeg+i+2, kB);
      QKS(sc, kA);
      PREAD(pa);
      EXPW(sc, tbeg+i+1);
      PVM(pa, vB);
      i += 2;
    }
    if(i < ntw){
      // one more tile (kB); PV of previous (vA); then drain
      LOADV(tbeg+i, vB);
      QKS(sc, kB);
      PREAD(pa);
      EXPW(sc, tbeg+i);
      PVM(pa, vA);
      PREAD(pa);
      PVM(pa, vB);
    } else {
      PREAD(pa);
      PVM(pa, vA);
    }
  }

  // exact merge of the two K-range partials (no max -> plain addition).
  // Osum/Lsum alias the P region -> barrier BEFORE the aliased write.
  __syncthreads();
  if(w==0){
    #pragma unroll
    for(int mt=0;mt<2;mt++){
      #pragma unroll
      for(int r=0;r<4;r++) Lsum[mt*16+g*4+r] = lacc[mt][r];
      #pragma unroll
      for(int df=0;df<4;df++)
        #pragma unroll
        for(int r=0;r<4;r++)
          Osum[(mt*16+g*4+r)*OSTR + df*16+c] = oacc[mt][df][r];
    }
  }
  __syncthreads();
  if(w==1){
    #pragma unroll
    for(int mt=0;mt<2;mt++){
      float linv[4];
      #pragma unroll
      for(int r=0;r<4;r++) linv[r] = 1.0f/(lacc[mt][r] + Lsum[mt*16+g*4+r]);
      int rowb = wrow + mt*16 + g*4;
      #pragma unroll
      for(int df=0;df<4;df++){
        int d = df*16 + c;
        #pragma unroll
        for(int r=0;r<4;r++){
          float v = oacc[mt][df][r] + Osum[(mt*16+g*4+r)*OSTR + d];
          O[((size_t)(b*SEQ + rowb + r))*DMODEL + hh*DHEAD + d] = f2bf(v*linv[r]);
        }
      }
    }
  }
}

// ---------------- launch ----------------
extern "C" void kernel_launch(void* const* d_in, const int* in_sizes, int n_in,
                              void* d_out, int out_size, void* d_ws, size_t ws_size,
                              hipStream_t stream){
  const float* x    = (const float*)d_in[0];
  const float* W_in = (const float*)d_in[1];
  const float* W_o  = (const float*)d_in[2];
  u16* ws = (u16*)d_ws;
  const size_t T16 = (size_t)8*1024*1024;  // 8M bf16 elems = 16 MB per tensor
  u16* h   = ws;            // [8192][1024] bf16
  u16* Qb  = ws +   T16;    // [64][2048][64]
  u16* Kb  = ws + 2*T16;    // [64][2048][64]
  u16* Vtb = ws + 3*T16;    // [64][64][2048]  (V transposed)
  u16* Wb  = ws + 4*T16;    // W_in bf16 [3072][1024]
  u16* Wob = Wb + (size_t)3*DMODEL*DMODEL; // W_o bf16 [1024][1024]
  u16* Ob  = h;             // reuse: h dead after gemm1
  float* out = (float*)d_out;

  const int na4 = 3*DMODEL*DMODEL/4;  // W_in float4 count
  const int nb4 = DMODEL*DMODEL/4;
  cast2_kernel<<<dim3((na4+nb4)/256), dim3(256), 0, stream>>>(W_in, Wb, W_o, Wob, na4);
  ln_kernel<<<dim3(MROWS), dim3(256), 0, stream>>>(x, h);
  gemm_bt<0><<<dim3(3*DMODEL/BN, MROWS/BM), dim3(256), 0, stream>>>(
      h, Wb, Qb, Kb, Vtb, nullptr, MROWS, 3*DMODEL, DMODEL);
  rope_kernel<<<dim3(SEQ*32/256), dim3(256), 0, stream>>>(Qb, Kb);
  attn_kernel<<<dim3(BHTOT, 64), dim3(128), 0, stream>>>(Qb, Kb, Vtb, Ob);
  gemm_bt<1><<<dim3(DMODEL/BN, MROWS/BM), dim3(256), 0, stream>>>(
      Ob, Wob, nullptr, nullptr, nullptr, out, MROWS, DMODEL, DMODEL);
}